// Round 8
// baseline (109.987 us; speedup 1.0000x reference)
//
#include <hip/hip_runtime.h>
#include <hip/hip_fp16.h>
#include <hip/hip_bf16.h>
#include <stdint.h>

// EXL3 linear: out = Had128( Had128(x*suh) @ dequant(trellis) ) * svh + bias
// B=8, K=4096, N=14336. Tiles are 16x16, 48 uint16 words per tile.

#define IN_F 4096
#define OUT_F 14336
#define BATCH 8
#define TN_TILES 896     // OUT_F/16
#define KSLICES 8
#define ITERS 16         // MFMA K-steps per kslice (each = 2 k-tiles = K:32)
#define XH_PAD 520       // 512 + 8: keeps ds_read_b128 16B-aligned, kills conflicts
#define RS128 0.08838834764831845f  // 1/sqrt(128)

typedef __attribute__((ext_vector_type(4))) float f32x4;
typedef __attribute__((ext_vector_type(8))) _Float16 f16x8;
typedef __attribute__((ext_vector_type(2))) unsigned short u16x2;

// Module-scope scratch -> zero dependence on ws_size.
__device__ float g_part[KSLICES * BATCH * OUT_F];    // per-kslice partials

// ---------------------------------------------------------------------------
// Main kernel. Grid (224, 8): wave wv of block bx owns tile-column
// tn = bx*4+wv for kslice ks (32 k-tiles). Fuses the input rotation.
//   PROLOGUE: (a) issue this wave's bulk trellis load (lane l: half-tile
//   l&1 of tile l>>1; 48 B = 3 dwordx4). (b) While those loads are in
//   flight, compute the block's own slice of the input rotation: rows 0..7,
//   k in [ks*512,(ks+1)*512) = 8 rows x 4 had-blocks; wave wv does rows
//   2wv..2wv+1 (FWHT128 butterflies via shuffles), storing f16 to xh_s.
//   (c) Build comb windows c[w] = u[w]<<16 | u[w+1] and ds_write to a
//   wave-private cwin slice. (d) ONE __syncthreads (for xh_s cross-wave).
//   K-LOOP (software-pipelined): prefetch iter it+1's 8 comb words (4
//   ds_read2_b32) and A-fragment (ds_read_b128 from xh_s) while decoding
//   iter it. Decode = QTIP 3INST LCG, hi-16 half in packed u16 math
//   (bit-identical: z>>16 = ((t>>16)+st*1361) mod 2^16 where
//   t = st*31858 + C, z = t + (st*1361<<16)).
//   EPILOGUE: plain coalesced stores to g_part[ks] (no atomics).
// B-frag: lane holds B[k=(lane>>4)*8+j][n=lane&15]. Weight (u=k&15, c=n&15)
// has bit offset 48u+3c -> word w0+3j, shift 16-((3c)&15), w0=3*r0+((3c)>>4).
__global__ __launch_bounds__(256) void k_main(const uint32_t* __restrict__ tr,
                                              const void* __restrict__ xp,
                                              const void* __restrict__ suhp) {
  __shared__ uint32_t cwin[4][32][48];   // 24 KB: [wave][tile][comb words]
  __shared__ _Float16 xh_s[BATCH][XH_PAD];  // 8.1 KB rotated input slice
  const int t = threadIdx.x;
  const int lane = t & 63;
  const int wv = t >> 6;
  const int tn = blockIdx.x * 4 + wv;
  const int ks = blockIdx.y;
  // transport self-probes (wave-uniform)
  const uint32_t fmt = __any((tr[lane] >> 16) != 0) ? 1u : 0u;
  const uint32_t ffmt =
      __any((((const uint32_t*)xp)[lane] & 0x1FFFu) != 0) ? 0u : 1u;

  // ---- (a) bulk trellis load ----
  const int tile = lane >> 1;   // 0..31
  const int h = lane & 1;       // which 24-u16 half of the tile
  uint32_t d[12];
  if (fmt) {
    const uint4* gp = (const uint4*)(tr +
        ((long)(ks * 32 + tile) * TN_TILES + tn) * 24 + h * 12);
    uint4 a0 = gp[0], a1 = gp[1], a2 = gp[2];
    d[0] = a0.x; d[1] = a0.y; d[2]  = a0.z; d[3]  = a0.w;
    d[4] = a1.x; d[5] = a1.y; d[6]  = a1.z; d[7]  = a1.w;
    d[8] = a2.x; d[9] = a2.y; d[10] = a2.z; d[11] = a2.w;
  } else {
    const uint4* gp = (const uint4*)(tr +
        ((long)(ks * 32 + tile) * TN_TILES + tn) * 48 + h * 24);
    uint4 b0 = gp[0], b1 = gp[1], b2 = gp[2];
    uint4 b3 = gp[3], b4 = gp[4], b5 = gp[5];
    d[0]  = __builtin_amdgcn_perm(b0.y, b0.x, 0x05040100u);
    d[1]  = __builtin_amdgcn_perm(b0.w, b0.z, 0x05040100u);
    d[2]  = __builtin_amdgcn_perm(b1.y, b1.x, 0x05040100u);
    d[3]  = __builtin_amdgcn_perm(b1.w, b1.z, 0x05040100u);
    d[4]  = __builtin_amdgcn_perm(b2.y, b2.x, 0x05040100u);
    d[5]  = __builtin_amdgcn_perm(b2.w, b2.z, 0x05040100u);
    d[6]  = __builtin_amdgcn_perm(b3.y, b3.x, 0x05040100u);
    d[7]  = __builtin_amdgcn_perm(b3.w, b3.z, 0x05040100u);
    d[8]  = __builtin_amdgcn_perm(b4.y, b4.x, 0x05040100u);
    d[9]  = __builtin_amdgcn_perm(b4.w, b4.z, 0x05040100u);
    d[10] = __builtin_amdgcn_perm(b5.y, b5.x, 0x05040100u);
    d[11] = __builtin_amdgcn_perm(b5.w, b5.z, 0x05040100u);
  }

  // ---- (b) fused input rotation (overlaps the trellis loads) ----
  #pragma unroll
  for (int uu = 0; uu < 8; ++uu) {
    const int row = 2 * wv + (uu >> 2);
    const int hb = uu & 3;
    const int col = ks * 512 + hb * 128 + lane;
    float x0, x1, s0, s1;
    if (ffmt) {
      const float* xx = (const float*)xp;
      const float* sh = (const float*)suhp;
      x0 = xx[row * IN_F + col];      x1 = xx[row * IN_F + col + 64];
      s0 = sh[col];                   s1 = sh[col + 64];
    } else {
      const __hip_bfloat16* xx = (const __hip_bfloat16*)xp;
      const __hip_bfloat16* sh = (const __hip_bfloat16*)suhp;
      x0 = __bfloat162float(xx[row * IN_F + col]);
      x1 = __bfloat162float(xx[row * IN_F + col + 64]);
      s0 = __bfloat162float(sh[col]);
      s1 = __bfloat162float(sh[col + 64]);
    }
    float v0 = x0 * s0 * RS128;
    float v1 = x1 * s1 * RS128;
    { float a = v0 + v1, s = v0 - v1; v0 = a; v1 = s; }  // distance-64 stage
    #pragma unroll
    for (int dd = 32; dd >= 1; dd >>= 1) {
      float w0 = __shfl_xor(v0, dd);
      float w1 = __shfl_xor(v1, dd);
      if (lane & dd) { v0 = w0 - v0; v1 = w1 - v1; }
      else           { v0 = v0 + w0; v1 = v1 + w1; }
    }
    xh_s[row][hb * 128 + lane]      = (_Float16)v0;
    xh_s[row][hb * 128 + lane + 64] = (_Float16)v1;
  }

  // ---- (c) comb windows -> wave-private cwin ----
  uint32_t dnext = __shfl(d[0], lane ^ 1, 64);  // partner supplies u[24]/wrap
  uint32_t c[24];
  #pragma unroll
  for (int m = 0; m < 12; ++m) {
    uint32_t nx = (m < 11) ? d[m + 1] : dnext;
    c[2 * m]     = (d[m] >> 16) | (d[m] << 16);
    c[2 * m + 1] = __builtin_amdgcn_perm(d[m], nx, 0x07060100u);
  }
  {
    uint32_t* wp = &cwin[wv][tile][h * 24];
    #pragma unroll
    for (int k = 0; k < 6; ++k)
      *(uint4*)(wp + 4 * k) = *(const uint4*)(c + 4 * k);
  }

  // ---- (d) one barrier: xh_s is written by all waves, read cross-wave ----
  __syncthreads();

  // ---- K-loop ----
  const int q = lane >> 4;           // k-octet 0..3
  const int cc = lane & 15;          // column within tile
  const int par = q >> 1;            // which tile of the K=32 pair
  const int w0 = 3 * ((q & 1) << 3) + ((3 * cc) >> 4);
  const uint32_t shr = 16u - (uint32_t)((3 * cc) & 15);  // 1..16
  const uint32_t* myc = &cwin[wv][par][w0];

  auto lds_fetch = [&](int it, uint32_t* dst) {
    const uint32_t* cb = myc + it * 96;   // 2 tiles per iter
    #pragma unroll
    for (int g = 0; g < 4; ++g) {         // pairs -> ds_read2_b32
      dst[2 * g]     = cb[6 * g];
      dst[2 * g + 1] = cb[6 * g + 3];
    }
  };
  auto a_fetch = [&](int it) -> f16x8 {
    f16x8 a = {0, 0, 0, 0, 0, 0, 0, 0};
    if (cc < 8)
      a = *(const f16x8*)(&xh_s[cc][it * 32 + q * 8]);
    return a;
  };

  f32x4 acc = {0.f, 0.f, 0.f, 0.f};
  uint32_t cwA[8];
  lds_fetch(0, cwA);
  f16x8 aA = a_fetch(0);

  #pragma unroll 4
  for (int it = 0; it < ITERS; ++it) {
    uint32_t cwN[8] = {0, 0, 0, 0, 0, 0, 0, 0};
    f16x8 aN = {0, 0, 0, 0, 0, 0, 0, 0};
    if (it + 1 < ITERS) {
      lds_fetch(it + 1, cwN);
      aN = a_fetch(it + 1);
    }

    union { __half2 h2[4]; f16x8 v; } bfrag;
    #pragma unroll
    for (int g = 0; g < 4; ++g) {
      uint32_t c0 = cwA[2 * g], c1 = cwA[2 * g + 1];
      uint32_t st0 = (c0 >> shr) & 0xFFFFu;   // v_bfe
      uint32_t st1 = (c1 >> shr) & 0xFFFFu;
      uint32_t t0 = __umul24(st0, 31858u) + 64248484u;  // v_mad_u32_u24
      uint32_t t1 = __umul24(st1, 31858u) + 64248484u;
      union { uint32_t u; u16x2 v; } sp, pm, th;
      sp.u = __builtin_amdgcn_perm(st1, st0, 0x05040100u); // (st0, st1) packed
      pm.v = sp.v * (u16x2){1361, 1361};                   // v_pk_mul_lo_u16
      th.u = __builtin_amdgcn_perm(t1, t0, 0x07060302u);   // (t0>>16, t1>>16)
      th.v = th.v + pm.v;                                  // v_pk_add_u16
      uint32_t hi = th.u & 0x8FFF8FFFu;
      uint32_t lo = __builtin_amdgcn_perm(t1, t0, 0x05040100u) & 0x8FFF8FFFu;
      __half2 ha = *(__half2*)&lo;
      __half2 hb = *(__half2*)&hi;
      bfrag.h2[g] = __hadd2(ha, hb);   // two finished weights, packed f16
    }

    acc = __builtin_amdgcn_mfma_f32_16x16x32_f16(aA, bfrag.v, acc, 0, 0, 0);

    #pragma unroll
    for (int g = 0; g < 8; ++g) cwA[g] = cwN[g];
    aA = aN;
  }

  // C layout: col = lane&15, row = (lane>>4)*4 + reg; rows 0..7 are real.
  if (q < 2) {
    const int n = tn * 16 + cc;
    #pragma unroll
    for (int rg = 0; rg < 4; ++rg)
      g_part[((ks * BATCH) + q * 4 + rg) * OUT_F + n] = acc[rg];
  }
}

// ---------------------------------------------------------------------------
// Output rotation: y = sum_ks g_part; out = FWHT128(y)/sqrt(128)*svh + bias.
// Self-probes the float transport format from x (same rule as k_main).
__global__ void k_rot_out(const void* __restrict__ xp,
                          const void* __restrict__ svhp,
                          const void* __restrict__ biasp,
                          void* __restrict__ outp) {
  const int nblk = blockIdx.x;   // 0..111
  const int row = blockIdx.y;    // 0..7
  const int lane = threadIdx.x;  // 0..63
  const uint32_t ffmt =
      __any((((const uint32_t*)xp)[lane] & 0x1FFFu) != 0) ? 0u : 1u;
  const int n0 = nblk * 128 + lane;
  float v0 = 0.f, v1 = 0.f;
  #pragma unroll
  for (int s = 0; s < KSLICES; ++s) {
    v0 += g_part[(s * BATCH + row) * OUT_F + n0];
    v1 += g_part[(s * BATCH + row) * OUT_F + n0 + 64];
  }
  v0 *= RS128; v1 *= RS128;
  { float a = v0 + v1, s = v0 - v1; v0 = a; v1 = s; }
  #pragma unroll
  for (int d = 32; d >= 1; d >>= 1) {
    float w0 = __shfl_xor(v0, d);
    float w1 = __shfl_xor(v1, d);
    if (lane & d) { v0 = w0 - v0; v1 = w1 - v1; }
    else          { v0 = v0 + w0; v1 = v1 + w1; }
  }
  if (ffmt) {
    const float* svh = (const float*)svhp;
    const float* bias = (const float*)biasp;
    float* out = (float*)outp;
    out[(long)row * OUT_F + n0]      = v0 * svh[n0] + bias[n0];
    out[(long)row * OUT_F + n0 + 64] = v1 * svh[n0 + 64] + bias[n0 + 64];
  } else {
    const __hip_bfloat16* svh = (const __hip_bfloat16*)svhp;
    const __hip_bfloat16* bias = (const __hip_bfloat16*)biasp;
    __hip_bfloat16* out = (__hip_bfloat16*)outp;
    out[(long)row * OUT_F + n0] = __float2bfloat16(
        v0 * __bfloat162float(svh[n0]) + __bfloat162float(bias[n0]));
    out[(long)row * OUT_F + n0 + 64] = __float2bfloat16(
        v1 * __bfloat162float(svh[n0 + 64]) + __bfloat162float(bias[n0 + 64]));
  }
}

// ---------------------------------------------------------------------------
extern "C" void kernel_launch(void* const* d_in, const int* in_sizes, int n_in,
                              void* d_out, int out_size, void* d_ws,
                              size_t ws_size, hipStream_t stream) {
  const void*     x    = d_in[0];
  const uint32_t* tr   = (const uint32_t*)d_in[1];
  const void*     suh  = d_in[2];
  const void*     svh  = d_in[3];
  const void*     bias = d_in[4];

  k_main<<<dim3(TN_TILES / 4, KSLICES), 256, 0, stream>>>(tr, x, suh);
  k_rot_out<<<dim3(OUT_F / 128, BATCH), 64, 0, stream>>>(x, svh, bias, d_out);
}

// Round 9
// 105.737 us; speedup vs baseline: 1.0402x; 1.0402x over previous
//
#include <hip/hip_runtime.h>
#include <hip/hip_fp16.h>
#include <hip/hip_bf16.h>
#include <stdint.h>

// EXL3 linear: out = Had128( Had128(x*suh) @ dequant(trellis) ) * svh + bias
// B=8, K=4096, N=14336. Tiles are 16x16, 48 uint16 words per tile.
// Round 9: round-7 structure (separate rot_in; fusion regressed — it added
// 224x-redundant VALU/DS work to saturated pipes). New: 2-wave blocks
// (12.3 KB LDS -> 13 blocks/CU = 26 waves, tail 17%->7%) + full K-unroll.

#define IN_F 4096
#define OUT_F 14336
#define BATCH 8
#define TN_TILES 896     // OUT_F/16
#define KSLICES 8
#define ITERS 16         // MFMA K-steps per kslice (each = 2 k-tiles = K:32)
#define RS128 0.08838834764831845f  // 1/sqrt(128)

typedef __attribute__((ext_vector_type(4))) float f32x4;
typedef __attribute__((ext_vector_type(8))) _Float16 f16x8;
typedef __attribute__((ext_vector_type(2))) unsigned short u16x2;

// Module-scope scratch -> zero dependence on ws_size.
__device__ _Float16 g_xh[BATCH * IN_F];              // rotated input, f16
__device__ float g_part[KSLICES * BATCH * OUT_F];    // per-kslice partials

// ---------------------------------------------------------------------------
// Input rotation: g_xh = FWHT128(x * suh) / sqrt(128), f16 [8][4096].
// Self-probes the float transport format (fp16-upcast-to-f32 has mantissa
// bits 12..0 == 0 on every word; raw-16-bit transport essentially never).
__global__ void k_rot_in(const void* __restrict__ xp,
                         const void* __restrict__ suhp) {
  const int b = blockIdx.x;          // 0..255 = 8 rows * 32 blocks
  const int row = b >> 5, blk = b & 31;
  const int lane = threadIdx.x;      // 0..63
  const uint32_t ffmt =
      __any((((const uint32_t*)xp)[lane] & 0x1FFFu) != 0) ? 0u : 1u;
  const int i0 = blk * 128 + lane;
  float x0, x1, s0, s1;
  if (ffmt) {
    const float* x = (const float*)xp;
    const float* sh = (const float*)suhp;
    x0 = x[row * IN_F + i0];      x1 = x[row * IN_F + i0 + 64];
    s0 = sh[i0];                  s1 = sh[i0 + 64];
  } else {
    const __hip_bfloat16* x = (const __hip_bfloat16*)xp;
    const __hip_bfloat16* sh = (const __hip_bfloat16*)suhp;
    x0 = __bfloat162float(x[row * IN_F + i0]);
    x1 = __bfloat162float(x[row * IN_F + i0 + 64]);
    s0 = __bfloat162float(sh[i0]);
    s1 = __bfloat162float(sh[i0 + 64]);
  }
  float v0 = x0 * s0 * RS128;
  float v1 = x1 * s1 * RS128;
  { float a = v0 + v1, s = v0 - v1; v0 = a; v1 = s; }  // distance-64 stage
  #pragma unroll
  for (int d = 32; d >= 1; d >>= 1) {
    float w0 = __shfl_xor(v0, d);
    float w1 = __shfl_xor(v1, d);
    if (lane & d) { v0 = w0 - v0; v1 = w1 - v1; }
    else          { v0 = v0 + w0; v1 = v1 + w1; }
  }
  g_xh[row * IN_F + i0]      = (_Float16)v0;
  g_xh[row * IN_F + i0 + 64] = (_Float16)v1;
}

// ---------------------------------------------------------------------------
// Main kernel. Grid (448, 8), block 128 (2 waves): wave wv of block bx owns
// tile-column tn = bx*2+wv for kslice ks (32 k-tiles).
//   PROLOGUE: lane l bulk-loads half a tile (tile l>>1, half l&1; 48 B =
//   3 dwordx4), builds comb windows c[w] = u[w]<<16 | u[w+1], writes them to
//   a wave-private LDS slice (6 ds_write_b128). Wave-private + same-wave DS
//   ordering => NO barriers anywhere.
//   K-LOOP (fully unrolled, register-pipelined): prefetch iter it+1's 8 comb
//   words (4 ds_read2_b32) and A-fragment (global dwordx4 from g_xh, L2-hot)
//   while decoding iter it. Decode = QTIP 3INST LCG, hi-16 half in packed
//   u16 math (bit-identical: z>>16 = ((t>>16)+st*1361) mod 2^16 where
//   t = st*31858 + C, z = t + (st*1361<<16)).
//   EPILOGUE: plain coalesced stores to g_part[ks] (no atomics).
// B-frag: lane holds B[k=(lane>>4)*8+j][n=lane&15]. Weight (u=k&15, c=n&15)
// has bit offset 48u+3c -> word w0+3j, shift 16-((3c)&15), w0=3*r0+((3c)>>4).
__global__ __launch_bounds__(128, 6) void k_main(const uint32_t* __restrict__ tr) {
  __shared__ uint32_t cwin[2][32][48];  // 12.3 KB: [wave][tile][comb words]
  const int t = threadIdx.x;
  const int lane = t & 63;
  const int wv = t >> 6;               // 0..1
  const int tn = blockIdx.x * 2 + wv;
  const int ks = blockIdx.y;
  // self-probe trellis transport: raw u16 (high halves nonzero) vs 1/int32
  const uint32_t fmt = __any((tr[lane] >> 16) != 0) ? 1u : 0u;

  // ---- prologue ----
  const int tile = lane >> 1;   // 0..31
  const int h = lane & 1;       // which 24-u16 half of the tile
  uint32_t d[12];
  if (fmt) {
    const uint4* gp = (const uint4*)(tr +
        ((long)(ks * 32 + tile) * TN_TILES + tn) * 24 + h * 12);
    uint4 a0 = gp[0], a1 = gp[1], a2 = gp[2];
    d[0] = a0.x; d[1] = a0.y; d[2]  = a0.z; d[3]  = a0.w;
    d[4] = a1.x; d[5] = a1.y; d[6]  = a1.z; d[7]  = a1.w;
    d[8] = a2.x; d[9] = a2.y; d[10] = a2.z; d[11] = a2.w;
  } else {
    const uint4* gp = (const uint4*)(tr +
        ((long)(ks * 32 + tile) * TN_TILES + tn) * 48 + h * 24);
    uint4 b0 = gp[0], b1 = gp[1], b2 = gp[2];
    uint4 b3 = gp[3], b4 = gp[4], b5 = gp[5];
    d[0]  = __builtin_amdgcn_perm(b0.y, b0.x, 0x05040100u);
    d[1]  = __builtin_amdgcn_perm(b0.w, b0.z, 0x05040100u);
    d[2]  = __builtin_amdgcn_perm(b1.y, b1.x, 0x05040100u);
    d[3]  = __builtin_amdgcn_perm(b1.w, b1.z, 0x05040100u);
    d[4]  = __builtin_amdgcn_perm(b2.y, b2.x, 0x05040100u);
    d[5]  = __builtin_amdgcn_perm(b2.w, b2.z, 0x05040100u);
    d[6]  = __builtin_amdgcn_perm(b3.y, b3.x, 0x05040100u);
    d[7]  = __builtin_amdgcn_perm(b3.w, b3.z, 0x05040100u);
    d[8]  = __builtin_amdgcn_perm(b4.y, b4.x, 0x05040100u);
    d[9]  = __builtin_amdgcn_perm(b4.w, b4.z, 0x05040100u);
    d[10] = __builtin_amdgcn_perm(b5.y, b5.x, 0x05040100u);
    d[11] = __builtin_amdgcn_perm(b5.w, b5.z, 0x05040100u);
  }
  uint32_t dnext = __shfl(d[0], lane ^ 1, 64);  // partner supplies u[24]/wrap
  uint32_t c[24];
  #pragma unroll
  for (int m = 0; m < 12; ++m) {
    uint32_t nx = (m < 11) ? d[m + 1] : dnext;
    c[2 * m]     = (d[m] >> 16) | (d[m] << 16);
    c[2 * m + 1] = __builtin_amdgcn_perm(d[m], nx, 0x07060100u);
  }
  {
    uint32_t* wp = &cwin[wv][tile][h * 24];
    #pragma unroll
    for (int k = 0; k < 6; ++k)
      *(uint4*)(wp + 4 * k) = *(const uint4*)(c + 4 * k);
  }
  // no barrier: each wave reads only its own slice (same-wave DS in-order)

  // ---- K-loop ----
  const int q = lane >> 4;           // k-octet 0..3
  const int cc = lane & 15;          // column within tile
  const int par = q >> 1;            // which tile of the K=32 pair
  const int w0 = 3 * ((q & 1) << 3) + ((3 * cc) >> 4);
  const uint32_t shr = 16u - (uint32_t)((3 * cc) & 15);  // 1..16
  const uint32_t* myc = &cwin[wv][par][w0];

  auto lds_fetch = [&](int it, uint32_t* dst) {
    const uint32_t* cb = myc + it * 96;   // 2 tiles per iter
    #pragma unroll
    for (int g = 0; g < 4; ++g) {         // pairs -> ds_read2_b32
      dst[2 * g]     = cb[6 * g];
      dst[2 * g + 1] = cb[6 * g + 3];
    }
  };
  auto a_fetch = [&](int it) -> f16x8 {
    f16x8 a = {0, 0, 0, 0, 0, 0, 0, 0};
    if (cc < 8)
      a = *(const f16x8*)(g_xh + cc * IN_F + ks * 512 + it * 32 + q * 8);
    return a;
  };

  f32x4 acc = {0.f, 0.f, 0.f, 0.f};
  uint32_t cwA[8];
  lds_fetch(0, cwA);
  f16x8 aA = a_fetch(0);

  #pragma unroll
  for (int it = 0; it < ITERS; ++it) {
    uint32_t cwN[8] = {0, 0, 0, 0, 0, 0, 0, 0};
    f16x8 aN = {0, 0, 0, 0, 0, 0, 0, 0};
    if (it + 1 < ITERS) {
      lds_fetch(it + 1, cwN);
      aN = a_fetch(it + 1);
    }

    union { __half2 h2[4]; f16x8 v; } bfrag;
    #pragma unroll
    for (int g = 0; g < 4; ++g) {
      uint32_t c0 = cwA[2 * g], c1 = cwA[2 * g + 1];
      uint32_t st0 = (c0 >> shr) & 0xFFFFu;   // v_bfe
      uint32_t st1 = (c1 >> shr) & 0xFFFFu;
      uint32_t t0 = __umul24(st0, 31858u) + 64248484u;  // v_mad_u32_u24
      uint32_t t1 = __umul24(st1, 31858u) + 64248484u;
      union { uint32_t u; u16x2 v; } sp, pm, th;
      sp.u = __builtin_amdgcn_perm(st1, st0, 0x05040100u); // (st0, st1) packed
      pm.v = sp.v * (u16x2){1361, 1361};                   // v_pk_mul_lo_u16
      th.u = __builtin_amdgcn_perm(t1, t0, 0x07060302u);   // (t0>>16, t1>>16)
      th.v = th.v + pm.v;                                  // v_pk_add_u16
      uint32_t hi = th.u & 0x8FFF8FFFu;
      uint32_t lo = __builtin_amdgcn_perm(t1, t0, 0x05040100u) & 0x8FFF8FFFu;
      __half2 ha = *(__half2*)&lo;
      __half2 hb = *(__half2*)&hi;
      bfrag.h2[g] = __hadd2(ha, hb);   // two finished weights, packed f16
    }

    acc = __builtin_amdgcn_mfma_f32_16x16x32_f16(aA, bfrag.v, acc, 0, 0, 0);

    #pragma unroll
    for (int g = 0; g < 8; ++g) cwA[g] = cwN[g];
    aA = aN;
  }

  // C layout: col = lane&15, row = (lane>>4)*4 + reg; rows 0..7 are real.
  // Plain coalesced stores to this kslice's partial slice (no atomics).
  if (q < 2) {
    const int n = tn * 16 + cc;
    #pragma unroll
    for (int rg = 0; rg < 4; ++rg)
      g_part[((ks * BATCH) + q * 4 + rg) * OUT_F + n] = acc[rg];
  }
}

// ---------------------------------------------------------------------------
// Output rotation: y = sum_ks g_part; out = FWHT128(y)/sqrt(128)*svh + bias.
// Self-probes the float transport format from x (same rule as k_rot_in).
__global__ void k_rot_out(const void* __restrict__ xp,
                          const void* __restrict__ svhp,
                          const void* __restrict__ biasp,
                          void* __restrict__ outp) {
  const int nblk = blockIdx.x;   // 0..111
  const int row = blockIdx.y;    // 0..7
  const int lane = threadIdx.x;  // 0..63
  const uint32_t ffmt =
      __any((((const uint32_t*)xp)[lane] & 0x1FFFu) != 0) ? 0u : 1u;
  const int n0 = nblk * 128 + lane;
  float v0 = 0.f, v1 = 0.f;
  #pragma unroll
  for (int s = 0; s < KSLICES; ++s) {
    v0 += g_part[(s * BATCH + row) * OUT_F + n0];
    v1 += g_part[(s * BATCH + row) * OUT_F + n0 + 64];
  }
  v0 *= RS128; v1 *= RS128;
  { float a = v0 + v1, s = v0 - v1; v0 = a; v1 = s; }
  #pragma unroll
  for (int d = 32; d >= 1; d >>= 1) {
    float w0 = __shfl_xor(v0, d);
    float w1 = __shfl_xor(v1, d);
    if (lane & d) { v0 = w0 - v0; v1 = w1 - v1; }
    else          { v0 = v0 + w0; v1 = v1 + w1; }
  }
  if (ffmt) {
    const float* svh = (const float*)svhp;
    const float* bias = (const float*)biasp;
    float* out = (float*)outp;
    out[(long)row * OUT_F + n0]      = v0 * svh[n0] + bias[n0];
    out[(long)row * OUT_F + n0 + 64] = v1 * svh[n0 + 64] + bias[n0 + 64];
  } else {
    const __hip_bfloat16* svh = (const __hip_bfloat16*)svhp;
    const __hip_bfloat16* bias = (const __hip_bfloat16*)biasp;
    __hip_bfloat16* out = (__hip_bfloat16*)outp;
    out[(long)row * OUT_F + n0] = __float2bfloat16(
        v0 * __bfloat162float(svh[n0]) + __bfloat162float(bias[n0]));
    out[(long)row * OUT_F + n0 + 64] = __float2bfloat16(
        v1 * __bfloat162float(svh[n0 + 64]) + __bfloat162float(bias[n0 + 64]));
  }
}

// ---------------------------------------------------------------------------
extern "C" void kernel_launch(void* const* d_in, const int* in_sizes, int n_in,
                              void* d_out, int out_size, void* d_ws,
                              size_t ws_size, hipStream_t stream) {
  const void*     x    = d_in[0];
  const uint32_t* tr   = (const uint32_t*)d_in[1];
  const void*     suh  = d_in[2];
  const void*     svh  = d_in[3];
  const void*     bias = d_in[4];

  k_rot_in<<<256, 64, 0, stream>>>(x, suh);
  k_main<<<dim3(TN_TILES / 2, KSLICES), 128, 0, stream>>>(tr);
  k_rot_out<<<dim3(OUT_F / 128, BATCH), 64, 0, stream>>>(x, svh, bias, d_out);
}

// Round 10
// 104.481 us; speedup vs baseline: 1.0527x; 1.0120x over previous
//
#include <hip/hip_runtime.h>
#include <hip/hip_fp16.h>
#include <hip/hip_bf16.h>
#include <stdint.h>

// EXL3 linear: out = Had128( Had128(x*suh) @ dequant(trellis) ) * svh + bias
// B=8, K=4096, N=14336. Tiles are 16x16, 48 uint16 words per tile.
// Round 10: round-7 config (best: 103.9) + mod-3-transposed cwin so each
// lane's 8 comb words are contiguous -> 2 ds_read_b128/iter (was 4
// ds_read2_b32). Round-8 fusion and round-9 occupancy experiments both
// regressed; DS-pipe pressure is the remaining lever.

#define IN_F 4096
#define OUT_F 14336
#define BATCH 8
#define TN_TILES 896     // OUT_F/16
#define KSLICES 8
#define ITERS 16         // MFMA K-steps per kslice (each = 2 k-tiles = K:32)
#define RS128 0.08838834764831845f  // 1/sqrt(128)

typedef __attribute__((ext_vector_type(4))) float f32x4;
typedef __attribute__((ext_vector_type(8))) _Float16 f16x8;
typedef __attribute__((ext_vector_type(2))) unsigned short u16x2;

// Module-scope scratch -> zero dependence on ws_size.
__device__ _Float16 g_xh[BATCH * IN_F];              // rotated input, f16
__device__ float g_part[KSLICES * BATCH * OUT_F];    // per-kslice partials

// ---------------------------------------------------------------------------
// Input rotation: g_xh = FWHT128(x * suh) / sqrt(128), f16 [8][4096].
// Self-probes the float transport format (fp16-upcast-to-f32 has mantissa
// bits 12..0 == 0 on every word; raw-16-bit transport essentially never).
__global__ void k_rot_in(const void* __restrict__ xp,
                         const void* __restrict__ suhp) {
  const int b = blockIdx.x;          // 0..255 = 8 rows * 32 blocks
  const int row = b >> 5, blk = b & 31;
  const int lane = threadIdx.x;      // 0..63
  const uint32_t ffmt =
      __any((((const uint32_t*)xp)[lane] & 0x1FFFu) != 0) ? 0u : 1u;
  const int i0 = blk * 128 + lane;
  float x0, x1, s0, s1;
  if (ffmt) {
    const float* x = (const float*)xp;
    const float* sh = (const float*)suhp;
    x0 = x[row * IN_F + i0];      x1 = x[row * IN_F + i0 + 64];
    s0 = sh[i0];                  s1 = sh[i0 + 64];
  } else {
    const __hip_bfloat16* x = (const __hip_bfloat16*)xp;
    const __hip_bfloat16* sh = (const __hip_bfloat16*)suhp;
    x0 = __bfloat162float(x[row * IN_F + i0]);
    x1 = __bfloat162float(x[row * IN_F + i0 + 64]);
    s0 = __bfloat162float(sh[i0]);
    s1 = __bfloat162float(sh[i0 + 64]);
  }
  float v0 = x0 * s0 * RS128;
  float v1 = x1 * s1 * RS128;
  { float a = v0 + v1, s = v0 - v1; v0 = a; v1 = s; }  // distance-64 stage
  #pragma unroll
  for (int d = 32; d >= 1; d >>= 1) {
    float w0 = __shfl_xor(v0, d);
    float w1 = __shfl_xor(v1, d);
    if (lane & d) { v0 = w0 - v0; v1 = w1 - v1; }
    else          { v0 = v0 + w0; v1 = v1 + w1; }
  }
  g_xh[row * IN_F + i0]      = (_Float16)v0;
  g_xh[row * IN_F + i0 + 64] = (_Float16)v1;
}

// ---------------------------------------------------------------------------
// Main kernel. Grid (224, 8), block 256 (4 waves): wave wv of block bx owns
// tile-column tn = bx*4+wv for kslice ks (32 k-tiles).
//   PROLOGUE: lane l bulk-loads half a tile (tile l>>1, half l&1; 48 B =
//   3 dwordx4), builds comb windows c[w] = u[w]<<16 | u[w+1], writes them to
//   a wave-private LDS slice in MOD-3-TRANSPOSED order: word w = 3a+r at
//   position [tile][r*16+a]. Wave-private + same-wave DS ordering => NO
//   barriers anywhere.
//   K-LOOP (software-pipelined, unroll 4): a lane's 8 comb words (w0+3j,
//   j=0..7 -> r=e const, a=a0..a0+7 contiguous) come from 2 ds_read_b128;
//   prefetch iter it+1's comb words + A-fragment (global dwordx4 from g_xh,
//   L2-hot) while decoding iter it. Decode = QTIP 3INST LCG, hi-16 half in
//   packed u16 math (bit-identical: z>>16 = ((t>>16)+st*1361) mod 2^16
//   where t = st*31858 + C, z = t + (st*1361<<16)).
//   EPILOGUE: plain coalesced stores to g_part[ks] (no atomics).
// B-frag: lane holds B[k=(lane>>4)*8+j][n=lane&15]. Weight (u=k&15, c=n&15)
// has bit offset 48u+3c -> word w0+3j with w0 = 24*(q&1) + e, e=(3c)>>4,
// shift 16-((3c)&15). In transposed coords: r=e, a = 8*(q&1)+j.
__global__ __launch_bounds__(256) void k_main(const uint32_t* __restrict__ tr) {
  __shared__ uint32_t cwin[4][32][48];  // 24 KB: [wave][tile][r*16+a]
  const int t = threadIdx.x;
  const int lane = t & 63;
  const int wv = t >> 6;               // 0..3
  const int tn = blockIdx.x * 4 + wv;
  const int ks = blockIdx.y;
  // self-probe trellis transport: raw u16 (high halves nonzero) vs 1/int32
  const uint32_t fmt = __any((tr[lane] >> 16) != 0) ? 1u : 0u;

  // ---- prologue ----
  const int tile = lane >> 1;   // 0..31
  const int h = lane & 1;       // which 24-u16 half of the tile
  uint32_t d[12];
  if (fmt) {
    const uint4* gp = (const uint4*)(tr +
        ((long)(ks * 32 + tile) * TN_TILES + tn) * 24 + h * 12);
    uint4 a0 = gp[0], a1 = gp[1], a2 = gp[2];
    d[0] = a0.x; d[1] = a0.y; d[2]  = a0.z; d[3]  = a0.w;
    d[4] = a1.x; d[5] = a1.y; d[6]  = a1.z; d[7]  = a1.w;
    d[8] = a2.x; d[9] = a2.y; d[10] = a2.z; d[11] = a2.w;
  } else {
    const uint4* gp = (const uint4*)(tr +
        ((long)(ks * 32 + tile) * TN_TILES + tn) * 48 + h * 24);
    uint4 b0 = gp[0], b1 = gp[1], b2 = gp[2];
    uint4 b3 = gp[3], b4 = gp[4], b5 = gp[5];
    d[0]  = __builtin_amdgcn_perm(b0.y, b0.x, 0x05040100u);
    d[1]  = __builtin_amdgcn_perm(b0.w, b0.z, 0x05040100u);
    d[2]  = __builtin_amdgcn_perm(b1.y, b1.x, 0x05040100u);
    d[3]  = __builtin_amdgcn_perm(b1.w, b1.z, 0x05040100u);
    d[4]  = __builtin_amdgcn_perm(b2.y, b2.x, 0x05040100u);
    d[5]  = __builtin_amdgcn_perm(b2.w, b2.z, 0x05040100u);
    d[6]  = __builtin_amdgcn_perm(b3.y, b3.x, 0x05040100u);
    d[7]  = __builtin_amdgcn_perm(b3.w, b3.z, 0x05040100u);
    d[8]  = __builtin_amdgcn_perm(b4.y, b4.x, 0x05040100u);
    d[9]  = __builtin_amdgcn_perm(b4.w, b4.z, 0x05040100u);
    d[10] = __builtin_amdgcn_perm(b5.y, b5.x, 0x05040100u);
    d[11] = __builtin_amdgcn_perm(b5.w, b5.z, 0x05040100u);
  }
  uint32_t dnext = __shfl(d[0], lane ^ 1, 64);  // partner supplies u[24]/wrap
  uint32_t c[24];
  #pragma unroll
  for (int m = 0; m < 12; ++m) {
    uint32_t nx = (m < 11) ? d[m + 1] : dnext;
    c[2 * m]     = (d[m] >> 16) | (d[m] << 16);
    c[2 * m + 1] = __builtin_amdgcn_perm(d[m], nx, 0x07060100u);
  }
  // transposed write: local word w (= h*24 + i) = 3a + r; group by r.
  // For this lane: r = i mod 3, a = h*8 + i/3  ->  [tile][r*16 + h*8 + i/3].
  {
    uint32_t* wp = &cwin[wv][tile][0];
    #pragma unroll
    for (int r = 0; r < 3; ++r) {
      uint4 g0 = {c[r], c[r + 3], c[r + 6],  c[r + 9]};
      uint4 g1 = {c[r + 12], c[r + 15], c[r + 18], c[r + 21]};
      *(uint4*)(wp + r * 16 + h * 8)     = g0;
      *(uint4*)(wp + r * 16 + h * 8 + 4) = g1;
    }
  }
  // no barrier: each wave reads only its own slice (same-wave DS in-order)

  // ---- K-loop ----
  const int q = lane >> 4;           // k-octet 0..3
  const int cc = lane & 15;          // column within tile
  const int par = q >> 1;            // which tile of the K=32 pair
  const int e = (3 * cc) >> 4;       // residue class (0..2)
  const int a0 = (q & 1) << 3;       // a-offset within residue row
  const uint32_t shr = 16u - (uint32_t)((3 * cc) & 15);  // 1..16
  const uint32_t* myc = &cwin[wv][par][e * 16 + a0];

  auto lds_fetch = [&](int it, uint32_t* dst) {
    const uint32_t* cb = myc + it * 96;   // advance 2 tiles per iter
    *(uint4*)(dst)     = *(const uint4*)(cb);      // words a0..a0+3
    *(uint4*)(dst + 4) = *(const uint4*)(cb + 4);  // words a0+4..a0+7
  };
  auto a_fetch = [&](int it) -> f16x8 {
    f16x8 a = {0, 0, 0, 0, 0, 0, 0, 0};
    if (cc < 8)
      a = *(const f16x8*)(g_xh + cc * IN_F + ks * 512 + it * 32 + q * 8);
    return a;
  };

  f32x4 acc = {0.f, 0.f, 0.f, 0.f};
  uint32_t cwA[8];
  lds_fetch(0, cwA);
  f16x8 aA = a_fetch(0);

  #pragma unroll 4
  for (int it = 0; it < ITERS; ++it) {
    uint32_t cwN[8] = {0, 0, 0, 0, 0, 0, 0, 0};
    f16x8 aN = {0, 0, 0, 0, 0, 0, 0, 0};
    if (it + 1 < ITERS) {
      lds_fetch(it + 1, cwN);
      aN = a_fetch(it + 1);
    }

    union { __half2 h2[4]; f16x8 v; } bfrag;
    #pragma unroll
    for (int g = 0; g < 4; ++g) {
      uint32_t c0 = cwA[2 * g], c1 = cwA[2 * g + 1];  // weights 2g, 2g+1
      uint32_t st0 = (c0 >> shr) & 0xFFFFu;   // v_bfe
      uint32_t st1 = (c1 >> shr) & 0xFFFFu;
      uint32_t t0 = __umul24(st0, 31858u) + 64248484u;  // v_mad_u32_u24
      uint32_t t1 = __umul24(st1, 31858u) + 64248484u;
      union { uint32_t u; u16x2 v; } sp, pm, th;
      sp.u = __builtin_amdgcn_perm(st1, st0, 0x05040100u); // (st0, st1) packed
      pm.v = sp.v * (u16x2){1361, 1361};                   // v_pk_mul_lo_u16
      th.u = __builtin_amdgcn_perm(t1, t0, 0x07060302u);   // (t0>>16, t1>>16)
      th.v = th.v + pm.v;                                  // v_pk_add_u16
      uint32_t hi = th.u & 0x8FFF8FFFu;
      uint32_t lo = __builtin_amdgcn_perm(t1, t0, 0x05040100u) & 0x8FFF8FFFu;
      __half2 ha = *(__half2*)&lo;
      __half2 hb = *(__half2*)&hi;
      bfrag.h2[g] = __hadd2(ha, hb);   // two finished weights, packed f16
    }

    acc = __builtin_amdgcn_mfma_f32_16x16x32_f16(aA, bfrag.v, acc, 0, 0, 0);

    #pragma unroll
    for (int g = 0; g < 8; ++g) cwA[g] = cwN[g];
    aA = aN;
  }

  // C layout: col = lane&15, row = (lane>>4)*4 + reg; rows 0..7 are real.
  // Plain coalesced stores to this kslice's partial slice (no atomics).
  if (q < 2) {
    const int n = tn * 16 + cc;
    #pragma unroll
    for (int rg = 0; rg < 4; ++rg)
      g_part[((ks * BATCH) + q * 4 + rg) * OUT_F + n] = acc[rg];
  }
}

// ---------------------------------------------------------------------------
// Output rotation: y = sum_ks g_part; out = FWHT128(y)/sqrt(128)*svh + bias.
// Self-probes the float transport format from x (same rule as k_rot_in).
__global__ void k_rot_out(const void* __restrict__ xp,
                          const void* __restrict__ svhp,
                          const void* __restrict__ biasp,
                          void* __restrict__ outp) {
  const int nblk = blockIdx.x;   // 0..111
  const int row = blockIdx.y;    // 0..7
  const int lane = threadIdx.x;  // 0..63
  const uint32_t ffmt =
      __any((((const uint32_t*)xp)[lane] & 0x1FFFu) != 0) ? 0u : 1u;
  const int n0 = nblk * 128 + lane;
  float v0 = 0.f, v1 = 0.f;
  #pragma unroll
  for (int s = 0; s < KSLICES; ++s) {
    v0 += g_part[(s * BATCH + row) * OUT_F + n0];
    v1 += g_part[(s * BATCH + row) * OUT_F + n0 + 64];
  }
  v0 *= RS128; v1 *= RS128;
  { float a = v0 + v1, s = v0 - v1; v0 = a; v1 = s; }
  #pragma unroll
  for (int d = 32; d >= 1; d >>= 1) {
    float w0 = __shfl_xor(v0, d);
    float w1 = __shfl_xor(v1, d);
    if (lane & d) { v0 = w0 - v0; v1 = w1 - v1; }
    else          { v0 = v0 + w0; v1 = v1 + w1; }
  }
  if (ffmt) {
    const float* svh = (const float*)svhp;
    const float* bias = (const float*)biasp;
    float* out = (float*)outp;
    out[(long)row * OUT_F + n0]      = v0 * svh[n0] + bias[n0];
    out[(long)row * OUT_F + n0 + 64] = v1 * svh[n0 + 64] + bias[n0 + 64];
  } else {
    const __hip_bfloat16* svh = (const __hip_bfloat16*)svhp;
    const __hip_bfloat16* bias = (const __hip_bfloat16*)biasp;
    __hip_bfloat16* out = (__hip_bfloat16*)outp;
    out[(long)row * OUT_F + n0] = __float2bfloat16(
        v0 * __bfloat162float(svh[n0]) + __bfloat162float(bias[n0]));
    out[(long)row * OUT_F + n0 + 64] = __float2bfloat16(
        v1 * __bfloat162float(svh[n0 + 64]) + __bfloat162float(bias[n0 + 64]));
  }
}

// ---------------------------------------------------------------------------
extern "C" void kernel_launch(void* const* d_in, const int* in_sizes, int n_in,
                              void* d_out, int out_size, void* d_ws,
                              size_t ws_size, hipStream_t stream) {
  const void*     x    = d_in[0];
  const uint32_t* tr   = (const uint32_t*)d_in[1];
  const void*     suh  = d_in[2];
  const void*     svh  = d_in[3];
  const void*     bias = d_in[4];

  k_rot_in<<<256, 64, 0, stream>>>(x, suh);
  k_main<<<dim3(TN_TILES / 4, KSLICES), 256, 0, stream>>>(tr);
  k_rot_out<<<dim3(OUT_F / 128, BATCH), 64, 0, stream>>>(x, svh, bias, d_out);
}